// Round 8
// baseline (108.845 us; speedup 1.0000x reference)
//
#include <hip/hip_runtime.h>
#include <hip/hip_bf16.h>

typedef __bf16 bf16x8 __attribute__((ext_vector_type(8)));
typedef float f32x16 __attribute__((ext_vector_type(16)));
typedef unsigned int u32x4 __attribute__((ext_vector_type(4)));
typedef unsigned short u16;

// Problem constants: T=16, N=128, D=512, M=4096, NT=2048, TEMP=0.1
// ws layout: zn bf16[4096*512] (4 MiB) | merged f32[4096*32] (512 KiB)
//          | possum f32[4096] | partial f32[16]
//
// merged[r][t] (t=0..31): partial sum of exp(10*z_r.z_j) over column-tile t,
// written by exactly one block with a PLAIN store:
//   t >= tr(r): row-write of triangular block (tr, t)
//   t <  tr(r): col-write (symmetry) of block (t, tr)
// -> complete, disjoint coverage; NO atomics anywhere in the pipeline.
// (r7 post-mortem: gemm was pinned at ~47us in every round regardless of
// spill/conflicts/staging path; the invariant was contended fp32 atomics
// into the 16KB expsum region — ~500 serialized line-RMWs per column-group
// across XCDs. Deferral (r5) kept per-line contention identical, which is
// why it changed nothing. This version has zero RMWs.)

// ---------------------------------------------------------------- normalize
// 1024 blocks x 256 threads; one wave per row, full-wave shfl_xor reduce.
__global__ void nrm_kernel(const float* __restrict__ z, u16* __restrict__ zn) {
    int tid = threadIdx.x;
    int l = tid & 63, w = tid >> 6;
    int row = blockIdx.x * 4 + w;
    const float4* src = (const float4*)(z + row * 512);
    float4 v0 = src[l];
    float4 v1 = src[l + 64];
    float ss = v0.x * v0.x + v0.y * v0.y + v0.z * v0.z + v0.w * v0.w
             + v1.x * v1.x + v1.y * v1.y + v1.z * v1.z + v1.w * v1.w;
#pragma unroll
    for (int off = 32; off; off >>= 1) ss += __shfl_xor(ss, off, 64);
    float sc = 1.0f / fmaxf(sqrtf(ss), 1e-8f);   // matches ref clamp
    __hip_bfloat16 b0[4], b1[4];
    b0[0] = __float2bfloat16(v0.x * sc); b0[1] = __float2bfloat16(v0.y * sc);
    b0[2] = __float2bfloat16(v0.z * sc); b0[3] = __float2bfloat16(v0.w * sc);
    b1[0] = __float2bfloat16(v1.x * sc); b1[1] = __float2bfloat16(v1.y * sc);
    b1[2] = __float2bfloat16(v1.z * sc); b1[3] = __float2bfloat16(v1.w * sc);
    uint2 p0, p1;
    __builtin_memcpy(&p0, b0, 8);
    __builtin_memcpy(&p1, b1, 8);
    ((uint2*)(zn + row * 512))[l] = p0;
    ((uint2*)(zn + row * 512))[l + 64] = p1;
}

// ------------------------------------------- symmetric GEMM (+pos tail)
// Blocks [0,528): triangular (ti<=tj) 128x128 tiles of the symmetric Gram.
//   Reg-staged coalesced loads (r5: global_load_lds scatter was suspect,
//   kept out), ds_write_b128 into K-major LDS, lane-linear conflict-free
//   ds_read_b128 (0 read conflicts, r4/r5 verified). Load-early/write-late
//   T14 split, one barrier per tile. Partials -> merged[][], plain stores.
// Blocks [528,656): pos work — 32x32 group Gram, possum[i] = 10*sum dot.
__global__ __launch_bounds__(256, 1) void gemm_kernel(const u16* __restrict__ zn,
                                                      float* __restrict__ merged,
                                                      float* __restrict__ possum) {
    __shared__ u16 Bt[2][32 * 512];            // 64 KiB double buffer

    int tid = threadIdx.x;
    int wave = tid >> 6;
    int l = tid & 63;
    int m = l & 31, h = l >> 5;

    if (blockIdx.x >= 528) {       // ---------------- positives tail
        if (tid < 64) {
            int g = blockIdx.x - 528;
            int grow = (m < 16) ? (g * 16 + m) : (2048 + g * 16 + (m - 16));
            const u32x4* src = (const u32x4*)(zn + grow * 512);
            f32x16 acc = {};
#pragma unroll
            for (int kc = 0; kc < 32; ++kc) {
                bf16x8 f = __builtin_bit_cast(bf16x8, src[h + 2 * kc]);
                acc = __builtin_amdgcn_mfma_f32_32x32x16_bf16(f, f, acc, 0, 0, 0);
            }
#pragma unroll
            for (int r = 0; r < 16; ++r) {
                int rrow = (r & 3) + 8 * (r >> 2) + 4 * h;
                float v = (rrow == m) ? 0.f : acc[r];
                v += __shfl_xor(v, 1, 64);
                v += __shfl_xor(v, 2, 64);
                v += __shfl_xor(v, 4, 64);
                v += __shfl_xor(v, 8, 64);
                v += __shfl_xor(v, 16, 64);
                if (m == 0) {
                    int gr = (rrow < 16) ? (g * 16 + rrow) : (2048 + g * 16 + (rrow - 16));
                    possum[gr] = v * 10.0f;   // plain store; fin is a separate launch
                }
            }
        }
        return;
    }

    // triangular decode: tile row ti has 32-ti tiles (tj = ti..31)
    int b = blockIdx.x;
    int ti = 0;
    while (b >= 32 - ti) { b -= 32 - ti; ++ti; }
    int tj = ti + b;

    int rowbase = ti * 128 + wave * 32;
    int colbase = tj * 128;
    bool diag = (ti == tj);

    // A fragments, full K=512: row rowbase+m, k-granule h+2*kc
    u32x4 a[32];
    const u32x4* arow = (const u32x4*)(zn + (rowbase + m) * 512);
#pragma unroll
    for (int kc = 0; kc < 32; ++kc) a[kc] = arow[h + 2 * kc];

    float racc[16];
#pragma unroll
    for (int r = 0; r < 16; ++r) racc[r] = 0.f;
    float colacc[4] = {0.f, 0.f, 0.f, 0.f};    // per-lane column partials (static idx)

    // staging geometry: thread (c = tid>>3, g0 = tid&7) owns granules
    // g = g0+8i of col c. Global load: coalesced (8 lanes cover 128B).
    // ds_write K-major: byte = (g>>1)*1024 + (g&1)*512 + c*16
    //                        = wbase + i*4096  (single base + imm offsets).
    int c = tid >> 3, g0 = tid & 7;
    int wbase = (g0 >> 1) * 1024 + (g0 & 1) * 512 + c * 16;
    const u32x4* zsrc = (const u32x4*)(zn + (colbase + c) * 512);

    u32x4 stg[8];
    {   // prologue: stage col-tile 0 into Bt[0]
#pragma unroll
        for (int i = 0; i < 8; ++i) stg[i] = zsrc[g0 + 8 * i];
        char* dst = (char*)Bt[0] + wbase;
#pragma unroll
        for (int i = 0; i < 8; ++i) *(u32x4*)(dst + i * 4096) = stg[i];
    }
    __syncthreads();

#pragma unroll
    for (int ct = 0; ct < 4; ++ct) {
        if (ct < 3) {   // issue next tile's loads early (hide under MFMA)
            // +32 rows = 32*512 u16 = 2048 u32x4 granules
            const u32x4* nsrc = zsrc + (ct + 1) * 2048;
#pragma unroll
            for (int i = 0; i < 8; ++i) stg[i] = nsrc[g0 + 8 * i];
        }
        const char* rb = (const char*)Bt[ct & 1] + l * 16;   // lane-linear base
        f32x16 acc = {};
#pragma unroll
        for (int kc = 0; kc < 32; ++kc) {
            bf16x8 bf = *(const bf16x8*)(rb + kc * 1024);    // conflict-free
            acc = __builtin_amdgcn_mfma_f32_32x32x16_bf16(
                __builtin_bit_cast(bf16x8, a[kc]), bf, acc, 0, 0, 0);
        }

        if (diag && ct == wave) {  // aligned sub-block: mask true diagonal
#pragma unroll
            for (int r = 0; r < 16; ++r) {
                int rrow = (r & 3) + 8 * (r >> 2) + 4 * h;
                if (rrow != m) racc[r] += __builtin_exp2f(acc[r] * 14.426950408889634f);
            }
        } else {
            float csum = 0.f;
#pragma unroll
            for (int r = 0; r < 16; ++r) {
                float e = __builtin_exp2f(acc[r] * 14.426950408889634f);
                racc[r] += e;
                csum += e;
            }
            colacc[ct] += csum;    // register only; no VMEM in the loop
        }

        if (ct < 3) {   // write staged tile into the other buffer
            char* dst = (char*)Bt[(ct + 1) & 1] + wbase;
#pragma unroll
            for (int i = 0; i < 8; ++i) *(u32x4*)(dst + i * 4096) = stg[i];
        }
        __syncthreads();           // staged tile visible; current reads done
    }

    // row sums -> merged[row][tj], PLAIN stores (disjoint ownership)
#pragma unroll
    for (int r = 0; r < 16; ++r) {
        float v = racc[r];
        v += __shfl_xor(v, 1, 64);
        v += __shfl_xor(v, 2, 64);
        v += __shfl_xor(v, 4, 64);
        v += __shfl_xor(v, 8, 64);
        v += __shfl_xor(v, 16, 64);
        if (m == 0) {
            int rrow = (r & 3) + 8 * (r >> 2) + 4 * h;
            merged[(rowbase + rrow) * 32 + tj] = v;
        }
    }

    // symmetric column sums -> merged[col][ti] (off-diag only): cross-wave
    // reduce via LDS (Bt dead after the loop's final barrier), plain stores.
    if (!diag) {
        float* colred = (float*)Bt;            // [4 waves][128 cols]
#pragma unroll
        for (int ct = 0; ct < 4; ++ct) {
            float v = colacc[ct] + __shfl_xor(colacc[ct], 32, 64);  // combine k-halves
            if (h == 0) colred[wave * 128 + ct * 32 + m] = v;
        }
        __syncthreads();
        if (tid < 128) {
            float s = colred[tid] + colred[128 + tid] + colred[256 + tid] + colred[384 + tid];
            merged[(colbase + tid) * 32 + ti] = s;
        }
    }
}

// ---------------------------------------------------------------- finalize A
// 16 blocks x 256 threads; thread = one row r: expsum_r = sum of merged[r][0..31]
// (8x float4, all slots valid by construction), loss_r = log - possum/31;
// block-reduce -> partial[block].
__global__ void finA_kernel(const float* __restrict__ merged,
                            const float* __restrict__ possum,
                            float* __restrict__ partial) {
    int tid = threadIdx.x;
    int r = blockIdx.x * 256 + tid;
    const float4* mrow = (const float4*)(merged + r * 32);
    float s = 0.f;
#pragma unroll
    for (int i = 0; i < 8; ++i) {
        float4 v = mrow[i];
        s += (v.x + v.y) + (v.z + v.w);
    }
    float loss = __logf(s) - possum[r] * (1.0f / 31.0f);
#pragma unroll
    for (int off = 32; off; off >>= 1) loss += __shfl_xor(loss, off, 64);
    __shared__ float red[4];
    if ((tid & 63) == 0) red[tid >> 6] = loss;
    __syncthreads();
    if (tid == 0) partial[blockIdx.x] = (red[0] + red[1]) + (red[2] + red[3]);
}

// ---------------------------------------------------------------- finalize B
__global__ void finB_kernel(const float* __restrict__ partial, float* __restrict__ out) {
    int l = threadIdx.x;           // 64
    float v = (l < 16) ? partial[l] : 0.f;
    v += __shfl_xor(v, 1, 64);
    v += __shfl_xor(v, 2, 64);
    v += __shfl_xor(v, 4, 64);
    v += __shfl_xor(v, 8, 64);
    if (l == 0) out[0] = v * (1.0f / 4096.0f);
}

extern "C" void kernel_launch(void* const* d_in, const int* in_sizes, int n_in,
                              void* d_out, int out_size, void* d_ws, size_t ws_size,
                              hipStream_t stream) {
    const float* z = (const float*)d_in[0];
    // d_in[1] (done) is provably dead: positive_mask reduces to block-diag + eye.
    u16* zn = (u16*)d_ws;
    float* merged = (float*)((char*)d_ws + (4u << 20));   // 4096*32 f32
    float* possum = merged + 4096 * 32;
    float* partial = possum + 4096;
    float* out = (float*)d_out;

    nrm_kernel<<<1024, 256, 0, stream>>>(z, zn);
    gemm_kernel<<<656, 256, 0, stream>>>(zn, merged, possum);   // 528 sym + 128 pos
    finA_kernel<<<16, 256, 0, stream>>>(merged, possum, partial);
    finB_kernel<<<1, 64, 0, stream>>>(partial, out);
}